// Round 12
// baseline (134.980 us; speedup 1.0000x reference)
//
#include <hip/hip_runtime.h>
#include <math.h>

// PhaseShift: out = unwrap(atan2(xi,xr) - atan2(xi[ch0],xr[ch0]), axis=F)
// Shapes: [N=16, CH=4, F=513, T=512] fp32.
//
// Single-pass register-resident version. R10/R11 proved occupancy & ILP are
// not the wall; the R6 skeleton's extra 50MB RMW write is. Each thread keeps
// q = pc + local-correction-prefix for its 32 rows IN REGISTERS across the
// scan, then writes each output exactly once (nt).
// Spill-proofing (lessons R2/R4/R8/R9): 512-thr block (1024-thr blocks are
// pinned to 64 VGPR), __launch_bounds__(512,1) -> 512 VGPR cap, q footprint
// 96 floats, FULLY static unroll (partial unroll = runtime index = scratch),
// compile-time trip counts everywhere (row 512 peeled into seg 15 scalars).
// Block = (n, t-tile of 32): 32 t-lanes x 16 segs of 32 rows; grid 256.
// dd bit-sequence unchanged (channel-fused a0, bounded exact mod, same
// per-column order) -- no pi-boundary lottery re-roll; only sum association
// moves (ULP noise, proven safe R5->R6->R10->R11).

#define NN    16
#define CHN   4
#define FF    513
#define TT    512
#define PLANE (FF * TT)      // 262656
#define NSEG  16
#define SEGB  32

__device__ __forceinline__ float phase_corr(float dd) {
    // np.unwrap step: ddmod = pymod(dd+pi, 2pi) - pi; edge rule; gate |dd|<pi.
    // dd in (-4pi, 4pi) -> x = dd+pi in (-3pi, 5pi): <=2 exact +-2pi steps.
    const float PIF  = 3.14159265358979323846f;   // 0x40490FDB
    const float TPIF = 6.28318530717958647692f;   // 0x40C90FDB = 2*PIF exactly
    float x = dd + PIF;
    x = (x >= TPIF) ? x - TPIF : x;
    x = (x >= TPIF) ? x - TPIF : x;
    x = (x < 0.0f)  ? x + TPIF : x;
    x = (x < 0.0f)  ? x + TPIF : x;
    float ddmod = x - PIF;
    if (ddmod == -PIF && dd > 0.0f) ddmod = PIF;
    return (fabsf(dd) < PIF) ? 0.0f : (ddmod - dd);
}

__global__ __launch_bounds__(512, 1) void phase_unwrap_kernel(
    const float* __restrict__ xr, const float* __restrict__ xi,
    float* __restrict__ out)
{
    const int tid = threadIdx.x;
    const int tl  = tid & 31;       // t within tile
    const int seg = tid >> 5;       // 0..15 F-segment (32 rows each)
    const int bid = blockIdx.x;
    const int tt  = bid & 15;       // 16 tiles of 32 t
    const int n   = bid >> 4;
    const int t   = tt * 32 + tl;

    const unsigned base = (unsigned)(n * CHN * PLANE) + (unsigned)t;
    const int f0 = seg * SEGB;

    __shared__ float segsum[3][NSEG][32];   // 6 KB

    // Boundary phases at f0-1 (segs 1..15).
    float pp0 = 0.f, pp1 = 0.f, pp2 = 0.f;
    if (seg > 0) {
        const unsigned o = base + (unsigned)(f0 - 1) * TT;
        const float a0 = atan2f(xi[o], xr[o]);
        pp0 = atan2f(xi[o + 1u * PLANE], xr[o + 1u * PLANE]) - a0;
        pp1 = atan2f(xi[o + 2u * PLANE], xr[o + 2u * PLANE]) - a0;
        pp2 = atan2f(xi[o + 3u * PLANE], xr[o + 3u * PLANE]) - a0;
    }

    // Pass 1: read-only streaming; q = pc + local corr prefix, in registers.
    float q0[SEGB], q1[SEGB], q2[SEGB];
    float acc0 = 0.f, acc1 = 0.f, acc2 = 0.f;
    unsigned off = base + (unsigned)f0 * TT;
    #pragma unroll
    for (int k = 0; k < SEGB; ++k, off += TT) {
        const float a0  = atan2f(xi[off], xr[off]);
        const float pc0 = atan2f(xi[off + 1u * PLANE], xr[off + 1u * PLANE]) - a0;
        const float pc1 = atan2f(xi[off + 2u * PLANE], xr[off + 2u * PLANE]) - a0;
        const float pc2 = atan2f(xi[off + 3u * PLANE], xr[off + 3u * PLANE]) - a0;
        if (seg > 0 || k > 0) {            // k is compile-time in unrolled body
            acc0 += phase_corr(pc0 - pp0);
            acc1 += phase_corr(pc1 - pp1);
            acc2 += phase_corr(pc2 - pp2);
        }
        q0[k] = pc0 + acc0;
        q1[k] = pc1 + acc1;
        q2[k] = pc2 + acc2;
        pp0 = pc0; pp1 = pc1; pp2 = pc2;
    }

    // Peeled row 512 (seg 15 only): scalar temps, compile-time structure.
    float e0 = 0.f, e1 = 0.f, e2 = 0.f;
    if (seg == NSEG - 1) {
        const unsigned o = base + 512u * TT;
        const float a0  = atan2f(xi[o], xr[o]);
        const float pc0 = atan2f(xi[o + 1u * PLANE], xr[o + 1u * PLANE]) - a0;
        const float pc1 = atan2f(xi[o + 2u * PLANE], xr[o + 2u * PLANE]) - a0;
        const float pc2 = atan2f(xi[o + 3u * PLANE], xr[o + 3u * PLANE]) - a0;
        e0 = pc0 + acc0 + phase_corr(pc0 - pp0);
        e1 = pc1 + acc1 + phase_corr(pc1 - pp1);
        e2 = pc2 + acc2 + phase_corr(pc2 - pp2);
    }

    segsum[0][seg][tl] = acc0;
    segsum[1][seg][tl] = acc1;
    segsum[2][seg][tl] = acc2;
    __syncthreads();

    // Exclusive prefix over segments (broadcast LDS reads, predicated).
    float run0 = 0.f, run1 = 0.f, run2 = 0.f;
    #pragma unroll
    for (int v = 0; v < NSEG - 1; ++v) {
        if (v < seg) {
            run0 += segsum[0][v][tl];
            run1 += segsum[1][v][tl];
            run2 += segsum[2][v][tl];
        }
    }

    // Final pass: single nt write per output element (ch0 = exact zeros).
    unsigned o2 = base + (unsigned)f0 * TT;
    #pragma unroll
    for (int k = 0; k < SEGB; ++k, o2 += TT) {
        __builtin_nontemporal_store(0.0f,        &out[o2]);
        __builtin_nontemporal_store(q0[k] + run0, &out[o2 + 1u * PLANE]);
        __builtin_nontemporal_store(q1[k] + run1, &out[o2 + 2u * PLANE]);
        __builtin_nontemporal_store(q2[k] + run2, &out[o2 + 3u * PLANE]);
    }
    if (seg == NSEG - 1) {
        const unsigned o = base + 512u * TT;
        __builtin_nontemporal_store(0.0f,      &out[o]);
        __builtin_nontemporal_store(e0 + run0, &out[o + 1u * PLANE]);
        __builtin_nontemporal_store(e1 + run1, &out[o + 2u * PLANE]);
        __builtin_nontemporal_store(e2 + run2, &out[o + 3u * PLANE]);
    }
}

extern "C" void kernel_launch(void* const* d_in, const int* in_sizes, int n_in,
                              void* d_out, int out_size, void* d_ws, size_t ws_size,
                              hipStream_t stream) {
    const float* xr = (const float*)d_in[0];
    const float* xi = (const float*)d_in[1];
    float* out = (float*)d_out;

    dim3 grid(NN * 16);    // 256 blocks = 1 block/CU
    dim3 block(512);       // 16 segments x 32 t-lanes
    phase_unwrap_kernel<<<grid, block, 0, stream>>>(xr, xi, out);
}

// Round 13
// 68.074 us; speedup vs baseline: 1.9828x; 1.9828x over previous
//
#include <hip/hip_runtime.h>
#include <math.h>

// PhaseShift: out = unwrap(atan2(xi,xr) - atan2(xi[ch0],xr[ch0]), axis=F)
// Shapes: [N=16, CH=4, F=513, T=512] fp32.
//
// LDS-scratch single-write version. Register q spilled in every config
// (R2/R4/R8/R9/R12: compiler caps VGPR and dumps arrays to scratch), and
// the R6 skeleton's pass-1 ch1-3 stores cost +46MB of HBM double-writes
// (evicted before the pass-2 RMW; 6.3MB/XCD > 4MB L2). Fix: q = pc + local
// correction prefix lives in LDS -- each thread re-reads only ITS OWN q,
// so LDS is per-thread scratch: zero VGPR cost, cannot spill.
// Block = (n, t-tile of 32), 1024 thr = 32 t-lanes x 32 segs of 8 rows,
// processing F in 2 sequential chunks of 256 rows (compile-time trip
// counts everywhere -- R9 lesson), carrying the per-column correction
// total between chunks; row 512 peeled into seg-31 scalars. qlds[j][tid]
// layout -> bank = tid%32 -> 2-way conflict = free (m136). Every output
// (incl. ch0 zeros) written EXACTLY ONCE, nontemporal.
// dd bit-sequence unchanged (channel-fused a0, bounded exact mod, same
// per-column order; boundary rows re-read with identical expressions) --
// no pi-boundary lottery re-roll; only sum association moves (ULP noise,
// proven safe R5->R6->R10->R11).

#define NN     16
#define CHN    4
#define FF     513
#define TT     512
#define PLANE  (FF * TT)     // 262656
#define NSEG   32
#define SEGB   8             // rows per segment per chunk
#define CHUNK  256           // rows per chunk
#define NCHUNK 2
#define QSTRIDE 1024         // qlds[j][tid]

__device__ __forceinline__ float phase_corr(float dd) {
    // np.unwrap step: ddmod = pymod(dd+pi, 2pi) - pi; edge rule; gate |dd|<pi.
    // dd in (-4pi, 4pi) -> x = dd+pi in (-3pi, 5pi): <=2 exact +-2pi steps.
    const float PIF  = 3.14159265358979323846f;   // 0x40490FDB
    const float TPIF = 6.28318530717958647692f;   // 0x40C90FDB = 2*PIF exactly
    float x = dd + PIF;
    x = (x >= TPIF) ? x - TPIF : x;
    x = (x >= TPIF) ? x - TPIF : x;
    x = (x < 0.0f)  ? x + TPIF : x;
    x = (x < 0.0f)  ? x + TPIF : x;
    float ddmod = x - PIF;
    if (ddmod == -PIF && dd > 0.0f) ddmod = PIF;
    return (fabsf(dd) < PIF) ? 0.0f : (ddmod - dd);
}

__global__ __launch_bounds__(1024) void phase_unwrap_kernel(
    const float* __restrict__ xr, const float* __restrict__ xi,
    float* __restrict__ out)
{
    extern __shared__ float qlds[];          // [3*SEGB][1024] = 96 KB

    const int tid = threadIdx.x;
    const int tl  = tid & 31;       // t within tile
    const int seg = tid >> 5;       // 0..31 F-segment
    const int bid = blockIdx.x;
    const int tt  = bid & 15;       // 16 tiles of 32 t
    const int n   = bid >> 4;
    const int t   = tt * 32 + tl;

    const unsigned base = (unsigned)(n * CHN * PLANE) + (unsigned)t;

    __shared__ float segsum[3][NSEG][32];    // 12 KB

    float carry0 = 0.f, carry1 = 0.f, carry2 = 0.f;
    float pp0 = 0.f, pp1 = 0.f, pp2 = 0.f;   // persists into the row-512 peel

    for (int c = 0; c < NCHUNK; ++c) {
        const int f0 = c * CHUNK + seg * SEGB;

        // Boundary phases at f0-1 (every seg except global row 0).
        if (f0 > 0) {
            const unsigned o = base + (unsigned)(f0 - 1) * TT;
            const float a0 = atan2f(xi[o], xr[o]);
            pp0 = atan2f(xi[o + 1u * PLANE], xr[o + 1u * PLANE]) - a0;
            pp1 = atan2f(xi[o + 2u * PLANE], xr[o + 2u * PLANE]) - a0;
            pp2 = atan2f(xi[o + 3u * PLANE], xr[o + 3u * PLANE]) - a0;
        }

        // Pass 1: read inputs, q -> LDS scratch (own slots only).
        float acc0 = 0.f, acc1 = 0.f, acc2 = 0.f;
        unsigned off = base + (unsigned)f0 * TT;
        #pragma unroll
        for (int k = 0; k < SEGB; ++k, off += TT) {
            const float a0  = atan2f(xi[off], xr[off]);
            const float pc0 = atan2f(xi[off + 1u * PLANE], xr[off + 1u * PLANE]) - a0;
            const float pc1 = atan2f(xi[off + 2u * PLANE], xr[off + 2u * PLANE]) - a0;
            const float pc2 = atan2f(xi[off + 3u * PLANE], xr[off + 3u * PLANE]) - a0;
            if (f0 > 0 || k > 0) {           // k is compile-time here
                acc0 += phase_corr(pc0 - pp0);
                acc1 += phase_corr(pc1 - pp1);
                acc2 += phase_corr(pc2 - pp2);
            }
            qlds[(0 * SEGB + k) * QSTRIDE + tid] = pc0 + acc0;
            qlds[(1 * SEGB + k) * QSTRIDE + tid] = pc1 + acc1;
            qlds[(2 * SEGB + k) * QSTRIDE + tid] = pc2 + acc2;
            pp0 = pc0; pp1 = pc1; pp2 = pc2;
        }

        segsum[0][seg][tl] = acc0;
        segsum[1][seg][tl] = acc1;
        segsum[2][seg][tl] = acc2;
        __syncthreads();

        // run = carry + exclusive prefix; tot = carry + full sum (next carry).
        float run0 = carry0, run1 = carry1, run2 = carry2;
        float tot0 = carry0, tot1 = carry1, tot2 = carry2;
        #pragma unroll
        for (int v = 0; v < NSEG; ++v) {
            const float s0 = segsum[0][v][tl];
            const float s1 = segsum[1][v][tl];
            const float s2 = segsum[2][v][tl];
            if (v < seg) { run0 += s0; run1 += s1; run2 += s2; }
            tot0 += s0; tot1 += s1; tot2 += s2;
        }

        // Final stores: exactly one nt write per output element.
        unsigned o2 = base + (unsigned)f0 * TT;
        #pragma unroll
        for (int k = 0; k < SEGB; ++k, o2 += TT) {
            const float v0 = qlds[(0 * SEGB + k) * QSTRIDE + tid] + run0;
            const float v1 = qlds[(1 * SEGB + k) * QSTRIDE + tid] + run1;
            const float v2 = qlds[(2 * SEGB + k) * QSTRIDE + tid] + run2;
            __builtin_nontemporal_store(0.0f, &out[o2]);
            __builtin_nontemporal_store(v0, &out[o2 + 1u * PLANE]);
            __builtin_nontemporal_store(v1, &out[o2 + 2u * PLANE]);
            __builtin_nontemporal_store(v2, &out[o2 + 3u * PLANE]);
        }

        carry0 = tot0; carry1 = tot1; carry2 = tot2;
        __syncthreads();   // all segsum/qlds reads done before next chunk rewrites
    }

    // Peeled row 512: seg 31 holds pp = pc at row 511; carry = total corr 1..511.
    if (seg == NSEG - 1) {
        const unsigned o = base + 512u * TT;
        const float a0  = atan2f(xi[o], xr[o]);
        const float pc0 = atan2f(xi[o + 1u * PLANE], xr[o + 1u * PLANE]) - a0;
        const float pc1 = atan2f(xi[o + 2u * PLANE], xr[o + 2u * PLANE]) - a0;
        const float pc2 = atan2f(xi[o + 3u * PLANE], xr[o + 3u * PLANE]) - a0;
        __builtin_nontemporal_store(0.0f, &out[o]);
        __builtin_nontemporal_store(pc0 + carry0 + phase_corr(pc0 - pp0), &out[o + 1u * PLANE]);
        __builtin_nontemporal_store(pc1 + carry1 + phase_corr(pc1 - pp1), &out[o + 2u * PLANE]);
        __builtin_nontemporal_store(pc2 + carry2 + phase_corr(pc2 - pp2), &out[o + 3u * PLANE]);
    }
}

extern "C" void kernel_launch(void* const* d_in, const int* in_sizes, int n_in,
                              void* d_out, int out_size, void* d_ws, size_t ws_size,
                              hipStream_t stream) {
    const float* xr = (const float*)d_in[0];
    const float* xi = (const float*)d_in[1];
    float* out = (float*)d_out;

    dim3 grid(NN * 16);       // 256 blocks = 1 block/CU
    dim3 block(1024);         // 32 segments x 32 t-lanes
    const size_t shmem = 3 * SEGB * QSTRIDE * sizeof(float);   // 96 KB dynamic
    phase_unwrap_kernel<<<grid, block, shmem, stream>>>(xr, xi, out);
}

// Round 14
// 56.290 us; speedup vs baseline: 2.3979x; 1.2093x over previous
//
#include <hip/hip_runtime.h>
#include <math.h>

// PhaseShift: out = unwrap(atan2(xi,xr) - atan2(xi[ch0],xr[ch0]), axis=F)
// Shapes: [N=16, CH=4, F=513, T=512] fp32.
//
// Chunked-scan single-HBM-write version. R6's +46MB double-write +46MB
// re-fetch exists because pass-1 dirty lines (6.3MB/XCD) evict from the
// 4MB L2 before pass-2 re-reads. Fix: process F in 8 chunks of 64 rows;
// the pass1->pass2 window is ~3MB/XCD -> RMW hits L2, each out-line goes
// to HBM once. Segment boundaries pass pc through LDS (bit-exact), so the
// 31 boundary-row atan2 recomputes of R6 disappear (atan2 rows = 513).
// Spill rules obeyed: NO per-thread arrays, static inner trip counts,
// ~30 live floats (1024-thr 64-VGPR wall).
// Block = (n, t-tile of 32): 32 segs x 32 tl, seg owns 2 rows per chunk;
// grid 256. Per chunk: pass1 (pc, q=pc+acc regular store, ch0 nt zero,
// stash last-pc in dbuf LDS) | barrier | corr_first from neighbor's LDS
// last-pc; segsum = acc+cf | barrier | scan (+carry), RMW own rows (+run,
// nt final). Row 512 peeled into seg-31 scalars. Two barriers/chunk are
// sufficient (pcL double-buffered; barrier arrival order fences races).
// dd bit-sequence BIT-IDENTICAL to R6 (LDS passes exact bits; same fused
// a0 expressions, same per-column order) -- no pi-boundary lottery
// re-roll; only sum association moves (ULP noise, proven safe R5->R13).

#define NN     16
#define CHN    4
#define FF     513
#define TT     512
#define PLANE  (FF * TT)     // 262656
#define NSEG   32
#define SEGB   2             // rows per seg per chunk
#define CHUNK  64            // rows per chunk
#define NCHUNK 8             // 8*64 = 512 rows + peeled row 512

__device__ __forceinline__ float phase_corr(float dd) {
    // np.unwrap step: ddmod = pymod(dd+pi, 2pi) - pi; edge rule; gate |dd|<pi.
    // dd in (-4pi, 4pi) -> x = dd+pi in (-3pi, 5pi): <=2 exact +-2pi steps.
    const float PIF  = 3.14159265358979323846f;   // 0x40490FDB
    const float TPIF = 6.28318530717958647692f;   // 0x40C90FDB = 2*PIF exactly
    float x = dd + PIF;
    x = (x >= TPIF) ? x - TPIF : x;
    x = (x >= TPIF) ? x - TPIF : x;
    x = (x < 0.0f)  ? x + TPIF : x;
    x = (x < 0.0f)  ? x + TPIF : x;
    float ddmod = x - PIF;
    if (ddmod == -PIF && dd > 0.0f) ddmod = PIF;
    return (fabsf(dd) < PIF) ? 0.0f : (ddmod - dd);
}

__global__ __launch_bounds__(1024) void phase_unwrap_kernel(
    const float* __restrict__ xr, const float* __restrict__ xi,
    float* __restrict__ out)
{
    const int tid = threadIdx.x;
    const int tl  = tid & 31;       // t within tile
    const int seg = tid >> 5;       // 0..31 F-segment
    const int bid = blockIdx.x;
    const int tt  = bid & 15;       // 16 tiles of 32 t
    const int n   = bid >> 4;
    const int t   = tt * 32 + tl;

    const unsigned base = (unsigned)(n * CHN * PLANE) + (unsigned)t;

    __shared__ float segsum[3][NSEG][32];      // 12 KB
    __shared__ float pcL[2][3][NSEG][32];      // 24 KB, double-buffered

    float carry0 = 0.f, carry1 = 0.f, carry2 = 0.f;
    float p5110 = 0.f, p5111 = 0.f, p5112 = 0.f;   // seg31: pc at row 511

    for (int c = 0; c < NCHUNK; ++c) {
        const int f0 = c * CHUNK + seg * SEGB;

        // Pass 1: pc chain over 2 rows; q = pc + internal prefix -> out
        // (regular store, stays L2-hot for the RMW); ch0 = nt zero.
        float pf0, pf1, pf2;                    // pc of first row
        float pp0, pp1, pp2;                    // running prev pc
        float acc0 = 0.f, acc1 = 0.f, acc2 = 0.f;
        unsigned off = base + (unsigned)f0 * TT;
        #pragma unroll
        for (int k = 0; k < SEGB; ++k, off += TT) {
            const float a0  = atan2f(xi[off], xr[off]);
            const float pc0 = atan2f(xi[off + 1u * PLANE], xr[off + 1u * PLANE]) - a0;
            const float pc1 = atan2f(xi[off + 2u * PLANE], xr[off + 2u * PLANE]) - a0;
            const float pc2 = atan2f(xi[off + 3u * PLANE], xr[off + 3u * PLANE]) - a0;
            if (k == 0) {
                pf0 = pc0; pf1 = pc1; pf2 = pc2;
            } else {
                acc0 += phase_corr(pc0 - pp0);
                acc1 += phase_corr(pc1 - pp1);
                acc2 += phase_corr(pc2 - pp2);
            }
            __builtin_nontemporal_store(0.0f, &out[off]);   // ch0: exact zero
            out[off + 1u * PLANE] = pc0 + acc0;
            out[off + 2u * PLANE] = pc1 + acc1;
            out[off + 3u * PLANE] = pc2 + acc2;
            pp0 = pc0; pp1 = pc1; pp2 = pc2;
        }

        pcL[c & 1][0][seg][tl] = pp0;   // last pc of this seg's span
        pcL[c & 1][1][seg][tl] = pp1;
        pcL[c & 1][2][seg][tl] = pp2;
        if (c == NCHUNK - 1 && seg == NSEG - 1) {
            p5110 = pp0; p5111 = pp1; p5112 = pp2;   // pc at row 511
        }
        __syncthreads();

        // corr_first from the neighbor's last pc (bit-exact via LDS).
        float cf0 = 0.f, cf1 = 0.f, cf2 = 0.f;
        if (c > 0 || seg > 0) {
            const int sb = (seg > 0) ? (c & 1) : ((c & 1) ^ 1);
            const int sv = (seg > 0) ? (seg - 1) : (NSEG - 1);
            cf0 = phase_corr(pf0 - pcL[sb][0][sv][tl]);
            cf1 = phase_corr(pf1 - pcL[sb][1][sv][tl]);
            cf2 = phase_corr(pf2 - pcL[sb][2][sv][tl]);
        }
        segsum[0][seg][tl] = acc0 + cf0;
        segsum[1][seg][tl] = acc1 + cf1;
        segsum[2][seg][tl] = acc2 + cf2;
        __syncthreads();

        // run = carry + exclusive prefix + cf; tot -> next carry.
        float run0 = carry0 + cf0, run1 = carry1 + cf1, run2 = carry2 + cf2;
        float tot0 = carry0, tot1 = carry1, tot2 = carry2;
        #pragma unroll
        for (int v = 0; v < NSEG; ++v) {
            const float s0 = segsum[0][v][tl];
            const float s1 = segsum[1][v][tl];
            const float s2 = segsum[2][v][tl];
            if (v < seg) { run0 += s0; run1 += s1; run2 += s2; }
            tot0 += s0; tot1 += s1; tot2 += s2;
        }

        // Pass 2: RMW own rows (L2-hot), nt final store.
        unsigned o2 = base + (unsigned)f0 * TT;
        #pragma unroll
        for (int k = 0; k < SEGB; ++k, o2 += TT) {
            const float v0 = out[o2 + 1u * PLANE] + run0;
            const float v1 = out[o2 + 2u * PLANE] + run1;
            const float v2 = out[o2 + 3u * PLANE] + run2;
            __builtin_nontemporal_store(v0, &out[o2 + 1u * PLANE]);
            __builtin_nontemporal_store(v1, &out[o2 + 2u * PLANE]);
            __builtin_nontemporal_store(v2, &out[o2 + 3u * PLANE]);
        }

        carry0 = tot0; carry1 = tot1; carry2 = tot2;
        // No third barrier needed: any next-chunk LDS write conflicting with
        // this chunk's reads is ordered by barrier arrival (see header).
    }

    // Peeled row 512 (seg 31): pp = pc at row 511; carry = total corr 1..511.
    if (seg == NSEG - 1) {
        const unsigned o = base + 512u * TT;
        const float a0  = atan2f(xi[o], xr[o]);
        const float pc0 = atan2f(xi[o + 1u * PLANE], xr[o + 1u * PLANE]) - a0;
        const float pc1 = atan2f(xi[o + 2u * PLANE], xr[o + 2u * PLANE]) - a0;
        const float pc2 = atan2f(xi[o + 3u * PLANE], xr[o + 3u * PLANE]) - a0;
        __builtin_nontemporal_store(0.0f, &out[o]);
        __builtin_nontemporal_store(pc0 + carry0 + phase_corr(pc0 - p5110), &out[o + 1u * PLANE]);
        __builtin_nontemporal_store(pc1 + carry1 + phase_corr(pc1 - p5111), &out[o + 2u * PLANE]);
        __builtin_nontemporal_store(pc2 + carry2 + phase_corr(pc2 - p5112), &out[o + 3u * PLANE]);
    }
}

extern "C" void kernel_launch(void* const* d_in, const int* in_sizes, int n_in,
                              void* d_out, int out_size, void* d_ws, size_t ws_size,
                              hipStream_t stream) {
    const float* xr = (const float*)d_in[0];
    const float* xi = (const float*)d_in[1];
    float* out = (float*)d_out;

    dim3 grid(NN * 16);       // 256 blocks = 1 block/CU, 16 waves/CU
    dim3 block(1024);         // 32 segments x 32 t-lanes
    phase_unwrap_kernel<<<grid, block, 0, stream>>>(xr, xi, out);
}